// Round 1
// baseline (2092.319 us; speedup 1.0000x reference)
//
#include <hip/hip_runtime.h>
#include <cstdint>
#include <cstddef>

#define NN 50000
#define EE 500000
#define RR 8
#define CC 128
#define BB 4
#define H3C 384

__global__ void zero_k(float* p, int n) {
  int i = blockIdx.x * 256 + threadIdx.x;
  if (i < n) p[i] = 0.f;
}

__global__ void count_k(const int* __restrict__ ei, const int* __restrict__ et, float* cnt) {
  int e = blockIdx.x * 256 + threadIdx.x;
  if (e >= EE) return;
  int d = ei[EE + e];
  int r = et[e];
  atomicAdd(&cnt[r * NN + d], 1.f);
}

__global__ void inv_k(float* cnt, int n) {
  int i = blockIdx.x * 256 + threadIdx.x;
  if (i < n) cnt[i] = 1.f / fmaxf(cnt[i], 1.f);
}

__global__ void copy_k(const float* __restrict__ a, float* __restrict__ b, int n) {
  int i = blockIdx.x * 256 + threadIdx.x;
  if (i < n) b[i] = a[i];
}

// Layer-1 scatter: agg[d][c] += inv_cnt[r][d] * sum_b comp1[r][b]*basis1[b][s][c]
__global__ void scatter1_k(const int* __restrict__ ei, const int* __restrict__ et,
                           const float* __restrict__ inv_cnt,
                           const float* __restrict__ basis1, const float* __restrict__ comp1,
                           float* __restrict__ agg) {
  long long idx = (long long)blockIdx.x * 256 + threadIdx.x;
  if (idx >= (long long)EE * CC) return;
  int e = (int)(idx >> 7);
  int c = (int)(idx & 127);
  int s = ei[e], d = ei[EE + e], r = et[e];
  float w = inv_cnt[r * NN + d];
  const float* cp = comp1 + r * BB;
  float v = cp[0] * basis1[((size_t)0 * NN + s) * CC + c]
          + cp[1] * basis1[((size_t)1 * NN + s) * CC + c]
          + cp[2] * basis1[((size_t)2 * NN + s) * CC + c]
          + cp[3] * basis1[((size_t)3 * NN + s) * CC + c];
  atomicAdd(&agg[(size_t)d * CC + c], v * w);
}

// Layers 2/3 scatter: agg[d][c] += inv_cnt[r][d] * hr[r][s][c]
__global__ void scatter2_k(const int* __restrict__ ei, const int* __restrict__ et,
                           const float* __restrict__ inv_cnt,
                           const float* __restrict__ hr, float* __restrict__ agg) {
  long long idx = (long long)blockIdx.x * 256 + threadIdx.x;
  if (idx >= (long long)EE * CC) return;
  int e = (int)(idx >> 7);
  int c = (int)(idx & 127);
  int s = ei[e], d = ei[EE + e], r = et[e];
  float w = inv_cnt[r * NN + d];
  float v = hr[((size_t)r * NN + s) * CC + c];
  atomicAdd(&agg[(size_t)d * CC + c], v * w);
}

__global__ void combine_k(const float* __restrict__ agg, const float* __restrict__ bias,
                          float* __restrict__ h3, int off) {
  int i = blockIdx.x * 256 + threadIdx.x;  // n*C + c
  if (i >= NN * CC) return;
  int n = i >> 7, c = i & 127;
  float v = agg[i] + bias[c];
  h3[(size_t)n * H3C + off + c] = fmaxf(v, 0.f);
}

// Build stacked weights: slots 0..7 = sum_b comp[r][b]*basis[b], slot 8 = root.
__global__ void makew_k(const float* __restrict__ basis, const float* __restrict__ comp,
                        const float* __restrict__ root, float* __restrict__ Wst, int in) {
  int i = blockIdx.x * 256 + threadIdx.x;
  int tot = 9 * in * CC;
  if (i >= tot) return;
  int r = i / (in * CC);
  int rem = i - r * (in * CC);
  float v;
  if (r < RR) {
    size_t stride = (size_t)in * CC;
    v = comp[r * BB + 0] * basis[0 * stride + rem]
      + comp[r * BB + 1] * basis[1 * stride + rem]
      + comp[r * BB + 2] * basis[2 * stride + rem]
      + comp[r * BB + 3] * basis[3 * stride + rem];
  } else {
    v = root[rem];
  }
  Wst[i] = v;
}

// hr[r][n][c] = X[n][:] @ Wst[r]  (r<8); r==8 writes agg[n][c] (root product).
// Block: 256 threads, 16 rows x 128 cols; each thread 8 rows, 1 col.
__global__ __launch_bounds__(256) void gemm_k(const float* __restrict__ X, int ldx, int in,
                                              const float* __restrict__ Wst,
                                              float* __restrict__ hr, float* __restrict__ agg) {
  int r = blockIdx.y;
  int row0 = blockIdx.x * 16;
  int t = threadIdx.x;
  int c = t & 127, rh = t >> 7;
  const float* W = Wst + (size_t)r * in * CC;
  __shared__ float xs[16][33];
  float acc[8];
#pragma unroll
  for (int j = 0; j < 8; ++j) acc[j] = 0.f;
  for (int k0 = 0; k0 < in; k0 += 32) {
    for (int i = t; i < 512; i += 256) {
      int rr = i >> 5, kk = i & 31;
      xs[rr][kk] = X[(size_t)(row0 + rr) * ldx + k0 + kk];
    }
    __syncthreads();
#pragma unroll
    for (int kk = 0; kk < 32; ++kk) {
      float wv = W[(size_t)(k0 + kk) * CC + c];
#pragma unroll
      for (int j = 0; j < 8; ++j) acc[j] += xs[rh + 2 * j][kk] * wv;
    }
    __syncthreads();
  }
  float* o = (r < RR) ? (hr + ((size_t)r * NN + row0) * CC) : (agg + (size_t)row0 * CC);
#pragma unroll
  for (int j = 0; j < 8; ++j) o[(size_t)(rh + 2 * j) * CC + c] = acc[j];
}

// In-place log_softmax over 384 channels; one 64-lane wave per node.
__global__ void logsoftmax_k(float* __restrict__ h) {
  int n = blockIdx.x;
  int l = threadIdx.x;
  float* row = h + (size_t)n * H3C;
  float vals[6];
  float m = -1e30f;
#pragma unroll
  for (int j = 0; j < 6; ++j) {
    vals[j] = row[l + 64 * j];
    m = fmaxf(m, vals[j]);
  }
#pragma unroll
  for (int off = 32; off > 0; off >>= 1) m = fmaxf(m, __shfl_xor(m, off));
  float s = 0.f;
#pragma unroll
  for (int j = 0; j < 6; ++j) s += expf(vals[j] - m);
#pragma unroll
  for (int off = 32; off > 0; off >>= 1) s += __shfl_xor(s, off);
  float ls = logf(s);
#pragma unroll
  for (int j = 0; j < 6; ++j) row[l + 64 * j] = vals[j] - m - ls;
}

extern "C" void kernel_launch(void* const* d_in, const int* in_sizes, int n_in,
                              void* d_out, int out_size, void* d_ws, size_t ws_size,
                              hipStream_t stream) {
  const int* ei = (const int*)d_in[0];
  const int* et = (const int*)d_in[1];
  const float* basis1 = (const float*)d_in[2];
  const float* comp1 = (const float*)d_in[3];
  const float* root1 = (const float*)d_in[4];
  const float* bias1 = (const float*)d_in[5];
  const float* basis_b0 = (const float*)d_in[6];
  const float* comp_b0 = (const float*)d_in[7];
  const float* root_b0 = (const float*)d_in[8];
  const float* bias_b0 = (const float*)d_in[9];
  const float* basis_b1 = (const float*)d_in[10];
  const float* comp_b1 = (const float*)d_in[11];
  const float* root_b1 = (const float*)d_in[12];
  const float* bias_b1 = (const float*)d_in[13];
  float* out = (float*)d_out;  // [N][384], used as h3 storage
  float* ws = (float*)d_ws;

  const size_t n_inv = (size_t)RR * NN;        // 400,000
  const size_t n_wst = (size_t)9 * 256 * CC;   // 294,912
  const size_t n_agg = (size_t)NN * CC;        // 6,400,000
  const size_t n_hr = (size_t)RR * NN * CC;    // 51,200,000
  float* inv_cnt = ws;
  float* Wst = inv_cnt + n_inv;
  float* agg = Wst + n_wst;
  float* hr = agg + n_agg;
  if (ws_size < (n_inv + n_wst + n_agg + n_hr) * sizeof(float)) return;

  const int SC_BLKS = (int)(((long long)EE * CC + 255) / 256);  // 250000
  const int NC_BLKS = (NN * CC + 255) / 256;                    // 25000

  // --- counts (shared by all layers) ---
  zero_k<<<(int)((n_inv + 255) / 256), 256, 0, stream>>>(inv_cnt, (int)n_inv);
  count_k<<<(EE + 255) / 256, 256, 0, stream>>>(ei, et, inv_cnt);
  inv_k<<<(int)((n_inv + 255) / 256), 256, 0, stream>>>(inv_cnt, (int)n_inv);

  // --- layer 1 ---
  copy_k<<<NC_BLKS, 256, 0, stream>>>(root1, agg, NN * CC);
  scatter1_k<<<SC_BLKS, 256, 0, stream>>>(ei, et, inv_cnt, basis1, comp1, agg);
  combine_k<<<NC_BLKS, 256, 0, stream>>>(agg, bias1, out, 0);

  // --- layer 2 (in = 128, x = out[:, 0:128]) ---
  makew_k<<<(9 * CC * CC + 255) / 256, 256, 0, stream>>>(basis_b0, comp_b0, root_b0, Wst, CC);
  dim3 g2(NN / 16, 9);
  gemm_k<<<g2, 256, 0, stream>>>(out, H3C, CC, Wst, hr, agg);
  scatter2_k<<<SC_BLKS, 256, 0, stream>>>(ei, et, inv_cnt, hr, agg);
  combine_k<<<NC_BLKS, 256, 0, stream>>>(agg, bias_b0, out, CC);

  // --- layer 3 (in = 256, x = out[:, 0:256]) ---
  makew_k<<<(9 * 2 * CC * CC + 255) / 256, 256, 0, stream>>>(basis_b1, comp_b1, root_b1, Wst, 2 * CC);
  gemm_k<<<g2, 256, 0, stream>>>(out, H3C, 2 * CC, Wst, hr, agg);
  scatter2_k<<<SC_BLKS, 256, 0, stream>>>(ei, et, inv_cnt, hr, agg);
  combine_k<<<NC_BLKS, 256, 0, stream>>>(agg, bias_b1, out, 2 * CC);

  // --- log_softmax in place ---
  logsoftmax_k<<<NN, 64, 0, stream>>>(out);
}

// Round 2
// 927.494 us; speedup vs baseline: 2.2559x; 2.2559x over previous
//
#include <hip/hip_runtime.h>
#include <cstdint>
#include <cstddef>

#define NN 50000
#define EE 500000
#define RR 8
#define CC 128
#define BB 4
#define H3C 384
#define NSLOT 9
#define NCOL 1152  // NSLOT * CC

typedef unsigned short ushort_t;
typedef __bf16 bf16x8 __attribute__((ext_vector_type(8)));
typedef float f32x4 __attribute__((ext_vector_type(4)));
typedef unsigned short u16x8 __attribute__((ext_vector_type(8)));

static __device__ __forceinline__ ushort_t f2bf(float f) {
  unsigned u = __float_as_uint(f);
  unsigned r = (u + 0x7fffu + ((u >> 16) & 1u)) >> 16;
  return (ushort_t)r;
}
static __device__ __forceinline__ float bf2f(ushort_t u) {
  return __uint_as_float(((unsigned)u) << 16);
}

__global__ void zero_k(float* p, int n) {
  int i = blockIdx.x * 256 + threadIdx.x;
  if (i < n) p[i] = 0.f;
}

__global__ void count_k(const int* __restrict__ ei, const int* __restrict__ et, float* cnt) {
  int e = blockIdx.x * 256 + threadIdx.x;
  if (e >= EE) return;
  int d = ei[EE + e];
  int r = et[e];
  atomicAdd(&cnt[r * NN + d], 1.f);
}

__global__ void inv_k(float* cnt, int n) {
  int i = blockIdx.x * 256 + threadIdx.x;
  if (i < n) cnt[i] = 1.f / fmaxf(cnt[i], 1.f);
}

__global__ void copy_k(const float* __restrict__ a, float* __restrict__ b, int n) {
  int i = blockIdx.x * 256 + threadIdx.x;
  if (i < n) b[i] = a[i];
}

// Layer-1 scatter: agg[d][c] += inv_cnt[r][d] * sum_b comp1[r][b]*basis1[b][s][c]
__global__ void scatter1_k(const int* __restrict__ ei, const int* __restrict__ et,
                           const float* __restrict__ inv_cnt,
                           const float* __restrict__ basis1, const float* __restrict__ comp1,
                           float* __restrict__ agg) {
  long long idx = (long long)blockIdx.x * 256 + threadIdx.x;
  if (idx >= (long long)EE * CC) return;
  int e = (int)(idx >> 7);
  int c = (int)(idx & 127);
  int s = ei[e], d = ei[EE + e], r = et[e];
  float w = inv_cnt[r * NN + d];
  const float* cp = comp1 + r * BB;
  float v = cp[0] * basis1[((size_t)0 * NN + s) * CC + c]
          + cp[1] * basis1[((size_t)1 * NN + s) * CC + c]
          + cp[2] * basis1[((size_t)2 * NN + s) * CC + c]
          + cp[3] * basis1[((size_t)3 * NN + s) * CC + c];
  atomicAdd(&agg[(size_t)d * CC + c], v * w);
}

// Layers 2/3 scatter: agg[d][c] += inv_cnt[r][d] * hr[r][s][c]   (hr in bf16)
__global__ void scatter2_k(const int* __restrict__ ei, const int* __restrict__ et,
                           const float* __restrict__ inv_cnt,
                           const ushort_t* __restrict__ hr, float* __restrict__ agg) {
  long long idx = (long long)blockIdx.x * 256 + threadIdx.x;
  if (idx >= (long long)EE * CC) return;
  int e = (int)(idx >> 7);
  int c = (int)(idx & 127);
  int s = ei[e], d = ei[EE + e], r = et[e];
  float w = inv_cnt[r * NN + d];
  float v = bf2f(hr[((size_t)r * NN + s) * CC + c]);
  atomicAdd(&agg[(size_t)d * CC + c], v * w);
}

// relu(agg+bias) -> h3 column block; optionally also write bf16 X copy.
__global__ void combine_k(const float* __restrict__ agg, const float* __restrict__ bias,
                          float* __restrict__ h3, int off, ushort_t* xb, int xoff) {
  int i = blockIdx.x * 256 + threadIdx.x;  // n*C + c
  if (i >= NN * CC) return;
  int n = i >> 7, c = i & 127;
  float v = fmaxf(agg[i] + bias[c], 0.f);
  h3[(size_t)n * H3C + off + c] = v;
  if (xb) xb[(size_t)n * 256 + xoff + c] = f2bf(v);
}

// Stacked transposed bf16 weights: Wt[slot*128 + c][k], slots 0..7 = relation, 8 = root.
__global__ void makew_k(const float* __restrict__ basis, const float* __restrict__ comp,
                        const float* __restrict__ root, ushort_t* __restrict__ Wt, int K) {
  int i = blockIdx.x * 256 + threadIdx.x;
  int tot = NSLOT * K * CC;
  if (i >= tot) return;
  int r = i / (K * CC);
  int rem = i - r * (K * CC);  // ii*128 + c
  float v;
  if (r < RR) {
    size_t st = (size_t)K * CC;
    v = comp[r * BB + 0] * basis[0 * st + rem]
      + comp[r * BB + 1] * basis[1 * st + rem]
      + comp[r * BB + 2] * basis[2 * st + rem]
      + comp[r * BB + 3] * basis[3 * st + rem];
  } else {
    v = root[rem];
  }
  int ii = rem >> 7, c = rem & 127;
  Wt[(size_t)(r * CC + c) * K + ii] = f2bf(v);
}

// Fused MFMA GEMM: hr[gc>>7][n][gc&127] = X[n][:] @ Wt[gc][:]  over 1152 cols.
// Slot 8 (cols 1024..1151) writes agg (f32) = X @ root.
// 64x64 tile per block, 4 waves, 16x16x32 bf16 MFMA.
#define PADB 40  // LDS row stride in bf16 elems (32 + 8 pad)
__global__ __launch_bounds__(256) void mfma_gemm_k(
    const ushort_t* __restrict__ Xb, int ldx, int Ktot,
    const ushort_t* __restrict__ Wt,
    ushort_t* __restrict__ hr, float* __restrict__ agg) {
  __shared__ ushort_t xs[64 * PADB];
  __shared__ ushort_t wls[64 * PADB];
  int t = threadIdx.x;
  int wave = t >> 6, lane = t & 63;
  int fr = lane & 15, fq = lane >> 4;
  int row0 = blockIdx.x * 64;
  int col0 = blockIdx.y * 64;
  int srow = t >> 2, sseg = t & 3;

  f32x4 acc[4];
#pragma unroll
  for (int cb = 0; cb < 4; ++cb) acc[cb] = (f32x4){0.f, 0.f, 0.f, 0.f};

  int gr = row0 + srow;
  if (gr >= NN) gr = NN - 1;
  const ushort_t* xsrc_base = Xb + (size_t)gr * ldx + sseg * 8;
  const ushort_t* wsrc_base = Wt + (size_t)(col0 + srow) * Ktot + sseg * 8;

  for (int k0 = 0; k0 < Ktot; k0 += 32) {
    u16x8 xv = *(const u16x8*)(xsrc_base + k0);
    u16x8 wv = *(const u16x8*)(wsrc_base + k0);
    __syncthreads();
    *(u16x8*)(xs + srow * PADB + sseg * 8) = xv;
    *(u16x8*)(wls + srow * PADB + sseg * 8) = wv;
    __syncthreads();
    bf16x8 a = *(const bf16x8*)(xs + (wave * 16 + fr) * PADB + fq * 8);
#pragma unroll
    for (int cb = 0; cb < 4; ++cb) {
      bf16x8 b = *(const bf16x8*)(wls + (cb * 16 + fr) * PADB + fq * 8);
      acc[cb] = __builtin_amdgcn_mfma_f32_16x16x32_bf16(a, b, acc[cb], 0, 0, 0);
    }
  }

#pragma unroll
  for (int cb = 0; cb < 4; ++cb) {
    int gc = col0 + cb * 16 + fr;
    int r = gc >> 7, c = gc & 127;
#pragma unroll
    for (int j = 0; j < 4; ++j) {
      int n = row0 + wave * 16 + fq * 4 + j;
      if (n < NN) {
        if (r < RR) hr[((size_t)r * NN + n) * CC + c] = f2bf(acc[cb][j]);
        else        agg[(size_t)n * CC + c] = acc[cb][j];
      }
    }
  }
}

// In-place log_softmax over 384 channels; one 64-lane wave per node.
__global__ void logsoftmax_k(float* __restrict__ h) {
  int n = blockIdx.x;
  int l = threadIdx.x;
  float* row = h + (size_t)n * H3C;
  float vals[6];
  float m = -1e30f;
#pragma unroll
  for (int j = 0; j < 6; ++j) {
    vals[j] = row[l + 64 * j];
    m = fmaxf(m, vals[j]);
  }
#pragma unroll
  for (int off = 32; off > 0; off >>= 1) m = fmaxf(m, __shfl_xor(m, off));
  float s = 0.f;
#pragma unroll
  for (int j = 0; j < 6; ++j) s += expf(vals[j] - m);
#pragma unroll
  for (int off = 32; off > 0; off >>= 1) s += __shfl_xor(s, off);
  float ls = logf(s);
#pragma unroll
  for (int j = 0; j < 6; ++j) row[l + 64 * j] = vals[j] - m - ls;
}

extern "C" void kernel_launch(void* const* d_in, const int* in_sizes, int n_in,
                              void* d_out, int out_size, void* d_ws, size_t ws_size,
                              hipStream_t stream) {
  const int* ei = (const int*)d_in[0];
  const int* et = (const int*)d_in[1];
  const float* basis1 = (const float*)d_in[2];
  const float* comp1 = (const float*)d_in[3];
  const float* root1 = (const float*)d_in[4];
  const float* bias1 = (const float*)d_in[5];
  const float* basis_b0 = (const float*)d_in[6];
  const float* comp_b0 = (const float*)d_in[7];
  const float* root_b0 = (const float*)d_in[8];
  const float* bias_b0 = (const float*)d_in[9];
  const float* basis_b1 = (const float*)d_in[10];
  const float* comp_b1 = (const float*)d_in[11];
  const float* root_b1 = (const float*)d_in[12];
  const float* bias_b1 = (const float*)d_in[13];
  float* out = (float*)d_out;  // [N][384], used as h3 storage
  char* ws = (char*)d_ws;

  const size_t n_inv = (size_t)RR * NN;            // 400,000 f32
  const size_t n_agg = (size_t)NN * CC;            // 6,400,000 f32
  const size_t n_hr  = (size_t)RR * NN * CC;       // 51,200,000 bf16
  const size_t n_xb  = (size_t)NN * 256;           // 12,800,000 bf16
  const size_t n_wt  = (size_t)NCOL * 256;         // 294,912 bf16 (max K=256)
  float* inv_cnt = (float*)ws;
  float* agg = inv_cnt + n_inv;
  ushort_t* hr = (ushort_t*)(agg + n_agg);
  ushort_t* xb = hr + n_hr;
  ushort_t* wt = xb + n_xb;
  size_t need = (n_inv + n_agg) * 4 + (n_hr + n_xb + n_wt) * 2;
  if (ws_size < need) return;

  const int SC_BLKS = (int)(((long long)EE * CC + 255) / 256);  // 250000
  const int NC_BLKS = (NN * CC + 255) / 256;                    // 25000
  dim3 gg((NN + 63) / 64, NCOL / 64);                           // (782, 18)

  // --- counts (shared by all layers) ---
  zero_k<<<(int)((n_inv + 255) / 256), 256, 0, stream>>>(inv_cnt, (int)n_inv);
  count_k<<<(EE + 255) / 256, 256, 0, stream>>>(ei, et, inv_cnt);
  inv_k<<<(int)((n_inv + 255) / 256), 256, 0, stream>>>(inv_cnt, (int)n_inv);

  // --- layer 1 ---
  copy_k<<<NC_BLKS, 256, 0, stream>>>(root1, agg, NN * CC);
  scatter1_k<<<SC_BLKS, 256, 0, stream>>>(ei, et, inv_cnt, basis1, comp1, agg);
  combine_k<<<NC_BLKS, 256, 0, stream>>>(agg, bias1, out, 0, xb, 0);

  // --- layer 2 (K = 128, X = xb[:, 0:128]) ---
  makew_k<<<(NSLOT * CC * CC + 255) / 256, 256, 0, stream>>>(basis_b0, comp_b0, root_b0, wt, CC);
  mfma_gemm_k<<<gg, 256, 0, stream>>>(xb, 256, CC, wt, hr, agg);
  scatter2_k<<<SC_BLKS, 256, 0, stream>>>(ei, et, inv_cnt, hr, agg);
  combine_k<<<NC_BLKS, 256, 0, stream>>>(agg, bias_b0, out, CC, xb, CC);

  // --- layer 3 (K = 256, X = xb[:, 0:256]) ---
  makew_k<<<(NSLOT * 2 * CC * CC + 255) / 256, 256, 0, stream>>>(basis_b1, comp_b1, root_b1, wt, 2 * CC);
  mfma_gemm_k<<<gg, 256, 0, stream>>>(xb, 256, 2 * CC, wt, hr, agg);
  scatter2_k<<<SC_BLKS, 256, 0, stream>>>(ei, et, inv_cnt, hr, agg);
  combine_k<<<NC_BLKS, 256, 0, stream>>>(agg, bias_b1, out, 2 * CC, nullptr, 0);

  // --- log_softmax in place ---
  logsoftmax_k<<<NN, 64, 0, stream>>>(out);
}

// Round 3
// 471.255 us; speedup vs baseline: 4.4399x; 1.9681x over previous
//
#include <hip/hip_runtime.h>
#include <cstdint>
#include <cstddef>

#define NN 50000
#define EE 500000
#define RR 8
#define CC 128
#define BB 4
#define H3C 384
#define NSLOT 9
#define NCOL 1152  // NSLOT * CC
#define NB 196     // ceil(NN/256)

typedef unsigned short ushort_t;
typedef __bf16 bf16x8 __attribute__((ext_vector_type(8)));
typedef float f32x4 __attribute__((ext_vector_type(4)));
typedef unsigned short u16x8 __attribute__((ext_vector_type(8)));

static __device__ __forceinline__ ushort_t f2bf(float f) {
  unsigned u = __float_as_uint(f);
  unsigned r = (u + 0x7fffu + ((u >> 16) & 1u)) >> 16;
  return (ushort_t)r;
}
static __device__ __forceinline__ float bf2f(ushort_t u) {
  return __uint_as_float(((unsigned)u) << 16);
}

__global__ void zero_int_k(int* p, int n) {
  int i = blockIdx.x * 256 + threadIdx.x;
  if (i < n) p[i] = 0;
}

__global__ void count_k(const int* __restrict__ ei, const int* __restrict__ et, int* cnt) {
  int e = blockIdx.x * 256 + threadIdx.x;
  if (e >= EE) return;
  int d = ei[EE + e];
  int r = et[e];
  atomicAdd(&cnt[r * NN + d], 1);
}

// Block-level exclusive scan of per-node degree (sum of per-relation counts).
__global__ __launch_bounds__(256) void scanA_k(const int* __restrict__ cnt_rd, int* off, int* bsum) {
  __shared__ int s[256];
  int t = threadIdx.x;
  int i = blockIdx.x * 256 + t;
  int v = 0;
  if (i < NN) {
#pragma unroll
    for (int r = 0; r < RR; ++r) v += cnt_rd[r * NN + i];
  }
  s[t] = v;
  __syncthreads();
  for (int d = 1; d < 256; d <<= 1) {
    int x = (t >= d) ? s[t - d] : 0;
    __syncthreads();
    s[t] += x;
    __syncthreads();
  }
  if (i < NN) off[i] = s[t] - v;
  if (t == 255) bsum[blockIdx.x] = s[255];
}

__global__ __launch_bounds__(256) void scanB_k(const int* __restrict__ bsum, int* bbase) {
  __shared__ int s[256];
  int t = threadIdx.x;
  int v = (t < NB) ? bsum[t] : 0;
  s[t] = v;
  __syncthreads();
  for (int d = 1; d < 256; d <<= 1) {
    int x = (t >= d) ? s[t - d] : 0;
    __syncthreads();
    s[t] += x;
    __syncthreads();
  }
  if (t < NB) bbase[t] = s[t] - v;
}

__global__ void scanC_k(int* off, const int* __restrict__ bbase) {
  int i = blockIdx.x * 256 + threadIdx.x;
  if (i < NN) off[i] += bbase[i >> 8];
  if (i == 0) off[NN] = EE;
}

// Scatter edges into CSR slots; payload = {src | (r<<20), bits(1/max(cnt_rd,1))}.
__global__ void fill_k(const int* __restrict__ ei, const int* __restrict__ et,
                       const int* __restrict__ cnt_rd, const int* __restrict__ off,
                       int* cur, uint2* __restrict__ payload) {
  int e = blockIdx.x * 256 + threadIdx.x;
  if (e >= EE) return;
  int s = ei[e], d = ei[EE + e], r = et[e];
  int pos = off[d] + atomicAdd(&cur[d], 1);
  float w = 1.0f / (float)max(cnt_rd[r * NN + d], 1);
  payload[pos] = make_uint2((unsigned)s | ((unsigned)r << 20), __float_as_uint(w));
}

// hr1[r][n][c] = bf16( sum_b comp1[r][b] * basis1[b][n][c] )
__global__ void makehr1_k(const float* __restrict__ basis1, const float* __restrict__ comp1,
                          ushort_t* __restrict__ hr) {
  int i = blockIdx.x * 256 + threadIdx.x;
  if (i >= NN * CC) return;
  const size_t st = (size_t)NN * CC;
  float b0 = basis1[i], b1 = basis1[st + i], b2 = basis1[2 * st + i], b3 = basis1[3 * st + i];
#pragma unroll
  for (int r = 0; r < RR; ++r) {
    float v = comp1[r * BB + 0] * b0 + comp1[r * BB + 1] * b1
            + comp1[r * BB + 2] * b2 + comp1[r * BB + 3] * b3;
    hr[(size_t)r * st + i] = f2bf(v);
  }
}

// Per-destination aggregation: one wave per node, lane handles channels 2l,2l+1.
// out row = relu(sum_edges w*hr_row + rootsrc[d] + bias); optional bf16 X copy.
__global__ __launch_bounds__(256) void aggr_k(const int* __restrict__ off,
                                              const uint2* __restrict__ payload,
                                              const ushort_t* __restrict__ hr,
                                              const float* __restrict__ rootsrc,
                                              const float* __restrict__ bias,
                                              float* __restrict__ h3, int hoff,
                                              ushort_t* xb, int xoff) {
  int wave = threadIdx.x >> 6, lane = threadIdx.x & 63;
  int d = blockIdx.x * 4 + wave;
  if (d >= NN) return;
  int beg = off[d], end = off[d + 1];
  float a0 = 0.f, a1 = 0.f;
  for (int i = beg; i < end; ++i) {
    uint2 pw = payload[i];
    unsigned sr = pw.x;
    const ushort_t* row = hr + ((size_t)(sr >> 20) * NN + (sr & 0xFFFFFu)) * CC + lane * 2;
    unsigned v = *(const unsigned*)row;
    float w = __uint_as_float(pw.y);
    a0 += w * bf2f((ushort_t)(v & 0xFFFFu));
    a1 += w * bf2f((ushort_t)(v >> 16));
  }
  int c = lane * 2;
  float v0 = fmaxf(a0 + rootsrc[(size_t)d * CC + c] + bias[c], 0.f);
  float v1 = fmaxf(a1 + rootsrc[(size_t)d * CC + c + 1] + bias[c + 1], 0.f);
  h3[(size_t)d * H3C + hoff + c] = v0;
  h3[(size_t)d * H3C + hoff + c + 1] = v1;
  if (xb) {
    unsigned pk = (unsigned)f2bf(v0) | ((unsigned)f2bf(v1) << 16);
    *(unsigned*)(xb + (size_t)d * 256 + xoff + c) = pk;
  }
}

// Stacked transposed bf16 weights: Wt[slot*128 + c][k], slots 0..7 = relation, 8 = root.
__global__ void makew_k(const float* __restrict__ basis, const float* __restrict__ comp,
                        const float* __restrict__ root, ushort_t* __restrict__ Wt, int K) {
  int i = blockIdx.x * 256 + threadIdx.x;
  int tot = NSLOT * K * CC;
  if (i >= tot) return;
  int r = i / (K * CC);
  int rem = i - r * (K * CC);  // ii*128 + c
  float v;
  if (r < RR) {
    size_t st = (size_t)K * CC;
    v = comp[r * BB + 0] * basis[0 * st + rem]
      + comp[r * BB + 1] * basis[1 * st + rem]
      + comp[r * BB + 2] * basis[2 * st + rem]
      + comp[r * BB + 3] * basis[3 * st + rem];
  } else {
    v = root[rem];
  }
  int ii = rem >> 7, c = rem & 127;
  Wt[(size_t)(r * CC + c) * K + ii] = f2bf(v);
}

// Fused MFMA GEMM: hr[gc>>7][n][gc&127] = X[n][:] @ Wt[gc][:]  over 1152 cols.
// Slot 8 (cols 1024..1151) writes aggroot (f32) = X @ root.
#define PADB 40
__global__ __launch_bounds__(256) void mfma_gemm_k(
    const ushort_t* __restrict__ Xb, int ldx, int Ktot,
    const ushort_t* __restrict__ Wt,
    ushort_t* __restrict__ hr, float* __restrict__ aggroot) {
  __shared__ ushort_t xs[64 * PADB];
  __shared__ ushort_t wls[64 * PADB];
  int t = threadIdx.x;
  int wave = t >> 6, lane = t & 63;
  int fr = lane & 15, fq = lane >> 4;
  int row0 = blockIdx.x * 64;
  int col0 = blockIdx.y * 64;
  int srow = t >> 2, sseg = t & 3;

  f32x4 acc[4];
#pragma unroll
  for (int cb = 0; cb < 4; ++cb) acc[cb] = (f32x4){0.f, 0.f, 0.f, 0.f};

  int gr = row0 + srow;
  if (gr >= NN) gr = NN - 1;
  const ushort_t* xsrc_base = Xb + (size_t)gr * ldx + sseg * 8;
  const ushort_t* wsrc_base = Wt + (size_t)(col0 + srow) * Ktot + sseg * 8;

  for (int k0 = 0; k0 < Ktot; k0 += 32) {
    u16x8 xv = *(const u16x8*)(xsrc_base + k0);
    u16x8 wv = *(const u16x8*)(wsrc_base + k0);
    __syncthreads();
    *(u16x8*)(xs + srow * PADB + sseg * 8) = xv;
    *(u16x8*)(wls + srow * PADB + sseg * 8) = wv;
    __syncthreads();
    bf16x8 a = *(const bf16x8*)(xs + (wave * 16 + fr) * PADB + fq * 8);
#pragma unroll
    for (int cb = 0; cb < 4; ++cb) {
      bf16x8 b = *(const bf16x8*)(wls + (cb * 16 + fr) * PADB + fq * 8);
      acc[cb] = __builtin_amdgcn_mfma_f32_16x16x32_bf16(a, b, acc[cb], 0, 0, 0);
    }
  }

#pragma unroll
  for (int cb = 0; cb < 4; ++cb) {
    int gc = col0 + cb * 16 + fr;
    int r = gc >> 7, c = gc & 127;
#pragma unroll
    for (int j = 0; j < 4; ++j) {
      int n = row0 + wave * 16 + fq * 4 + j;
      if (n < NN) {
        if (r < RR) hr[((size_t)r * NN + n) * CC + c] = f2bf(acc[cb][j]);
        else        aggroot[(size_t)n * CC + c] = acc[cb][j];
      }
    }
  }
}

// In-place log_softmax over 384 channels; one 64-lane wave per node.
__global__ void logsoftmax_k(float* __restrict__ h) {
  int n = blockIdx.x;
  int l = threadIdx.x;
  float* row = h + (size_t)n * H3C;
  float vals[6];
  float m = -1e30f;
#pragma unroll
  for (int j = 0; j < 6; ++j) {
    vals[j] = row[l + 64 * j];
    m = fmaxf(m, vals[j]);
  }
#pragma unroll
  for (int off = 32; off > 0; off >>= 1) m = fmaxf(m, __shfl_xor(m, off));
  float s = 0.f;
#pragma unroll
  for (int j = 0; j < 6; ++j) s += expf(vals[j] - m);
#pragma unroll
  for (int off = 32; off > 0; off >>= 1) s += __shfl_xor(s, off);
  float ls = logf(s);
#pragma unroll
  for (int j = 0; j < 6; ++j) row[l + 64 * j] = vals[j] - m - ls;
}

extern "C" void kernel_launch(void* const* d_in, const int* in_sizes, int n_in,
                              void* d_out, int out_size, void* d_ws, size_t ws_size,
                              hipStream_t stream) {
  const int* ei = (const int*)d_in[0];
  const int* et = (const int*)d_in[1];
  const float* basis1 = (const float*)d_in[2];
  const float* comp1 = (const float*)d_in[3];
  const float* root1 = (const float*)d_in[4];
  const float* bias1 = (const float*)d_in[5];
  const float* basis_b0 = (const float*)d_in[6];
  const float* comp_b0 = (const float*)d_in[7];
  const float* root_b0 = (const float*)d_in[8];
  const float* bias_b0 = (const float*)d_in[9];
  const float* basis_b1 = (const float*)d_in[10];
  const float* comp_b1 = (const float*)d_in[11];
  const float* root_b1 = (const float*)d_in[12];
  const float* bias_b1 = (const float*)d_in[13];
  float* out = (float*)d_out;  // [N][384] h3 storage
  char* ws = (char*)d_ws;

  // Layout (8B-aligned first):
  uint2* payload = (uint2*)ws;                                  // E * 8B = 4 MB
  float* aggroot = (float*)(payload + EE);                      // N*C f32 = 25.6 MB
  ushort_t* hr = (ushort_t*)(aggroot + (size_t)NN * CC);        // 8*N*C bf16 = 102.4 MB
  ushort_t* xb = hr + (size_t)RR * NN * CC;                     // N*256 bf16 = 25.6 MB
  ushort_t* wt = xb + (size_t)NN * 256;                         // 1152*256 bf16 = 0.59 MB
  int* cnt_rd = (int*)(wt + (size_t)NCOL * 256);                // R*N int = 1.6 MB
  int* cur = cnt_rd + (size_t)RR * NN;                          // N int
  int* off = cur + NN;                                          // (N+1) int
  int* bsum = off + NN + 1;                                     // NB
  int* bbase = bsum + 256;                                      // NB
  size_t need = (size_t)(bbase + 256) - (size_t)ws;
  if (ws_size < need) return;

  // --- CSR build ---
  zero_int_k<<<(RR * NN + NN + 255) / 256, 256, 0, stream>>>(cnt_rd, RR * NN + NN);  // cnt_rd + cur
  count_k<<<(EE + 255) / 256, 256, 0, stream>>>(ei, et, cnt_rd);
  scanA_k<<<NB, 256, 0, stream>>>(cnt_rd, off, bsum);
  scanB_k<<<1, 256, 0, stream>>>(bsum, bbase);
  scanC_k<<<NB, 256, 0, stream>>>(off, bbase);
  fill_k<<<(EE + 255) / 256, 256, 0, stream>>>(ei, et, cnt_rd, off, cur, payload);

  const int NC_BLKS = (NN * CC + 255) / 256;
  const int AG_BLKS = (NN + 3) / 4;
  dim3 gg((NN + 63) / 64, NCOL / 64);

  // --- layer 1 ---
  makehr1_k<<<NC_BLKS, 256, 0, stream>>>(basis1, comp1, hr);
  aggr_k<<<AG_BLKS, 256, 0, stream>>>(off, payload, hr, root1, bias1, out, 0, xb, 0);

  // --- layer 2 (K=128) ---
  makew_k<<<(NSLOT * CC * CC + 255) / 256, 256, 0, stream>>>(basis_b0, comp_b0, root_b0, wt, CC);
  mfma_gemm_k<<<gg, 256, 0, stream>>>(xb, 256, CC, wt, hr, aggroot);
  aggr_k<<<AG_BLKS, 256, 0, stream>>>(off, payload, hr, aggroot, bias_b0, out, CC, xb, CC);

  // --- layer 3 (K=256) ---
  makew_k<<<(NSLOT * 2 * CC * CC + 255) / 256, 256, 0, stream>>>(basis_b1, comp_b1, root_b1, wt, 2 * CC);
  mfma_gemm_k<<<gg, 256, 0, stream>>>(xb, 256, 2 * CC, wt, hr, aggroot);
  aggr_k<<<AG_BLKS, 256, 0, stream>>>(off, payload, hr, aggroot, bias_b1, out, 2 * CC, nullptr, 0);

  // --- log_softmax in place ---
  logsoftmax_k<<<NN, 64, 0, stream>>>(out);
}

// Round 4
// 364.038 us; speedup vs baseline: 5.7475x; 1.2945x over previous
//
#include <hip/hip_runtime.h>
#include <cstdint>
#include <cstddef>

#define NN 50000
#define EE 500000
#define RR 8
#define CC 128
#define BB 4
#define H3C 384
#define NSLOT 9
#define NCOL 1152  // NSLOT * CC
#define NT 18      // NCOL / 64 column tiles
#define NB 196     // ceil(NN/256)

typedef unsigned short ushort_t;
typedef __bf16 bf16x8 __attribute__((ext_vector_type(8)));
typedef float f32x4 __attribute__((ext_vector_type(4)));
typedef unsigned short u16x8 __attribute__((ext_vector_type(8)));

static __device__ __forceinline__ ushort_t f2bf(float f) {
  unsigned u = __float_as_uint(f);
  unsigned r = (u + 0x7fffu + ((u >> 16) & 1u)) >> 16;
  return (ushort_t)r;
}
static __device__ __forceinline__ float bf2f(ushort_t u) {
  return __uint_as_float(((unsigned)u) << 16);
}

__global__ void zero_int_k(int* p, int n) {
  int i = blockIdx.x * 256 + threadIdx.x;
  if (i < n) p[i] = 0;
}

__global__ void count_k(const int* __restrict__ ei, const int* __restrict__ et, int* cnt) {
  int e = blockIdx.x * 256 + threadIdx.x;
  if (e >= EE) return;
  int d = ei[EE + e];
  int r = et[e];
  atomicAdd(&cnt[r * NN + d], 1);
}

// Block-level exclusive scan of per-node degree (sum of per-relation counts).
__global__ __launch_bounds__(256) void scanA_k(const int* __restrict__ cnt_rd, int* off, int* bsum) {
  __shared__ int s[256];
  int t = threadIdx.x;
  int i = blockIdx.x * 256 + t;
  int v = 0;
  if (i < NN) {
#pragma unroll
    for (int r = 0; r < RR; ++r) v += cnt_rd[r * NN + i];
  }
  s[t] = v;
  __syncthreads();
  for (int d = 1; d < 256; d <<= 1) {
    int x = (t >= d) ? s[t - d] : 0;
    __syncthreads();
    s[t] += x;
    __syncthreads();
  }
  if (i < NN) off[i] = s[t] - v;
  if (t == 255) bsum[blockIdx.x] = s[255];
}

__global__ __launch_bounds__(256) void scanB_k(const int* __restrict__ bsum, int* bbase) {
  __shared__ int s[256];
  int t = threadIdx.x;
  int v = (t < NB) ? bsum[t] : 0;
  s[t] = v;
  __syncthreads();
  for (int d = 1; d < 256; d <<= 1) {
    int x = (t >= d) ? s[t - d] : 0;
    __syncthreads();
    s[t] += x;
    __syncthreads();
  }
  if (t < NB) bbase[t] = s[t] - v;
}

__global__ void scanC_k(int* off, const int* __restrict__ bbase) {
  int i = blockIdx.x * 256 + threadIdx.x;
  if (i < NN) off[i] += bbase[i >> 8];
  if (i == 0) off[NN] = EE;
}

// Scatter edges into CSR slots; payload = {src | (r<<20), bits(1/max(cnt_rd,1))}.
__global__ void fill_k(const int* __restrict__ ei, const int* __restrict__ et,
                       const int* __restrict__ cnt_rd, const int* __restrict__ off,
                       int* cur, uint2* __restrict__ payload) {
  int e = blockIdx.x * 256 + threadIdx.x;
  if (e >= EE) return;
  int s = ei[e], d = ei[EE + e], r = et[e];
  int pos = off[d] + atomicAdd(&cur[d], 1);
  float w = 1.0f / (float)max(cnt_rd[r * NN + d], 1);
  payload[pos] = make_uint2((unsigned)s | ((unsigned)r << 20), __float_as_uint(w));
}

// hr1[r][n][c] = bf16( sum_b comp1[r][b] * basis1[b][n][c] )
__global__ void makehr1_k(const float* __restrict__ basis1, const float* __restrict__ comp1,
                          ushort_t* __restrict__ hr) {
  int i = blockIdx.x * 256 + threadIdx.x;
  if (i >= NN * CC) return;
  const size_t st = (size_t)NN * CC;
  float b0 = basis1[i], b1 = basis1[st + i], b2 = basis1[2 * st + i], b3 = basis1[3 * st + i];
#pragma unroll
  for (int r = 0; r < RR; ++r) {
    float v = comp1[r * BB + 0] * b0 + comp1[r * BB + 1] * b1
            + comp1[r * BB + 2] * b2 + comp1[r * BB + 3] * b3;
    hr[(size_t)r * st + i] = f2bf(v);
  }
}

// Per-destination aggregation: one wave per node, lane handles channels 2l,2l+1.
__global__ __launch_bounds__(256) void aggr_k(const int* __restrict__ off,
                                              const uint2* __restrict__ payload,
                                              const ushort_t* __restrict__ hr,
                                              const float* __restrict__ rootsrc,
                                              const float* __restrict__ bias,
                                              float* __restrict__ h3, int hoff,
                                              ushort_t* xb, int xoff) {
  int wave = threadIdx.x >> 6, lane = threadIdx.x & 63;
  int d = blockIdx.x * 4 + wave;
  if (d >= NN) return;
  int beg = off[d], end = off[d + 1];
  float a0 = 0.f, a1 = 0.f;
  int i = beg;
  for (; i + 1 < end; i += 2) {
    uint2 p0 = payload[i], p1 = payload[i + 1];
    unsigned v0 = *(const unsigned*)(hr + ((size_t)(p0.x >> 20) * NN + (p0.x & 0xFFFFFu)) * CC + lane * 2);
    unsigned v1 = *(const unsigned*)(hr + ((size_t)(p1.x >> 20) * NN + (p1.x & 0xFFFFFu)) * CC + lane * 2);
    float w0 = __uint_as_float(p0.y), w1 = __uint_as_float(p1.y);
    a0 += w0 * bf2f((ushort_t)(v0 & 0xFFFFu));
    a1 += w0 * bf2f((ushort_t)(v0 >> 16));
    a0 += w1 * bf2f((ushort_t)(v1 & 0xFFFFu));
    a1 += w1 * bf2f((ushort_t)(v1 >> 16));
  }
  if (i < end) {
    uint2 p0 = payload[i];
    unsigned v0 = *(const unsigned*)(hr + ((size_t)(p0.x >> 20) * NN + (p0.x & 0xFFFFFu)) * CC + lane * 2);
    float w0 = __uint_as_float(p0.y);
    a0 += w0 * bf2f((ushort_t)(v0 & 0xFFFFu));
    a1 += w0 * bf2f((ushort_t)(v0 >> 16));
  }
  int c = lane * 2;
  float v0 = fmaxf(a0 + rootsrc[(size_t)d * CC + c] + bias[c], 0.f);
  float v1 = fmaxf(a1 + rootsrc[(size_t)d * CC + c + 1] + bias[c + 1], 0.f);
  h3[(size_t)d * H3C + hoff + c] = v0;
  h3[(size_t)d * H3C + hoff + c + 1] = v1;
  if (xb) {
    unsigned pk = (unsigned)f2bf(v0) | ((unsigned)f2bf(v1) << 16);
    *(unsigned*)(xb + (size_t)d * 256 + xoff + c) = pk;
  }
}

// Layer-3 aggregation with fused log_softmax over all 384 channels.
__global__ __launch_bounds__(256) void aggr_sm_k(const int* __restrict__ off,
                                                 const uint2* __restrict__ payload,
                                                 const ushort_t* __restrict__ hr,
                                                 const float* __restrict__ rootsrc,
                                                 const float* __restrict__ bias,
                                                 float* __restrict__ h3) {
  int wave = threadIdx.x >> 6, lane = threadIdx.x & 63;
  int d = blockIdx.x * 4 + wave;
  if (d >= NN) return;
  int beg = off[d], end = off[d + 1];
  float a0 = 0.f, a1 = 0.f;
  int i = beg;
  for (; i + 1 < end; i += 2) {
    uint2 p0 = payload[i], p1 = payload[i + 1];
    unsigned v0 = *(const unsigned*)(hr + ((size_t)(p0.x >> 20) * NN + (p0.x & 0xFFFFFu)) * CC + lane * 2);
    unsigned v1 = *(const unsigned*)(hr + ((size_t)(p1.x >> 20) * NN + (p1.x & 0xFFFFFu)) * CC + lane * 2);
    float w0 = __uint_as_float(p0.y), w1 = __uint_as_float(p1.y);
    a0 += w0 * bf2f((ushort_t)(v0 & 0xFFFFu));
    a1 += w0 * bf2f((ushort_t)(v0 >> 16));
    a0 += w1 * bf2f((ushort_t)(v1 & 0xFFFFu));
    a1 += w1 * bf2f((ushort_t)(v1 >> 16));
  }
  if (i < end) {
    uint2 p0 = payload[i];
    unsigned v0 = *(const unsigned*)(hr + ((size_t)(p0.x >> 20) * NN + (p0.x & 0xFFFFFu)) * CC + lane * 2);
    float w0 = __uint_as_float(p0.y);
    a0 += w0 * bf2f((ushort_t)(v0 & 0xFFFFu));
    a1 += w0 * bf2f((ushort_t)(v0 >> 16));
  }
  int c = lane * 2;
  float v0 = fmaxf(a0 + rootsrc[(size_t)d * CC + c] + bias[c], 0.f);
  float v1 = fmaxf(a1 + rootsrc[(size_t)d * CC + c + 1] + bias[c + 1], 0.f);
  float* row = h3 + (size_t)d * H3C;
  float vals[6];
  vals[0] = row[lane];
  vals[1] = row[lane + 64];
  vals[2] = row[lane + 128];
  vals[3] = row[lane + 192];
  // col 256+lane lives in v0/v1 of lane (lane>>1); col 320+lane in lane 32+(lane>>1).
  int s4 = lane >> 1;
  float e0 = __shfl(v0, s4), e1 = __shfl(v1, s4);
  vals[4] = (lane & 1) ? e1 : e0;
  int s5 = 32 + (lane >> 1);
  float g0 = __shfl(v0, s5), g1 = __shfl(v1, s5);
  vals[5] = (lane & 1) ? g1 : g0;
  float m = -1e30f;
#pragma unroll
  for (int j = 0; j < 6; ++j) m = fmaxf(m, vals[j]);
#pragma unroll
  for (int o = 32; o > 0; o >>= 1) m = fmaxf(m, __shfl_xor(m, o));
  float s = 0.f;
#pragma unroll
  for (int j = 0; j < 6; ++j) s += expf(vals[j] - m);
#pragma unroll
  for (int o = 32; o > 0; o >>= 1) s += __shfl_xor(s, o);
  float ls = logf(s);
#pragma unroll
  for (int j = 0; j < 6; ++j) row[lane + 64 * j] = vals[j] - m - ls;
}

// Fragment-major stacked weights:
// Wt[((ct*(K/32) + kk)*256 + cb*64 + lane)*8 + j] = W[kk*32 + (lane>>4)*8 + j][ct*64 + cb*16 + (lane&15)]
__global__ void makew2_k(const float* __restrict__ basis, const float* __restrict__ comp,
                         const float* __restrict__ root, ushort_t* __restrict__ Wt, int K) {
  int f = blockIdx.x * 256 + threadIdx.x;
  int perct = (K / 32) * 256;
  int tot = NT * perct;
  if (f >= tot) return;
  int ct = f / perct, rem = f - ct * perct;
  int kk = rem >> 8, rem2 = rem & 255;
  int cb = rem2 >> 6, l = rem2 & 63;
  int fr = l & 15, fq = l >> 4;
  int gc = ct * 64 + cb * 16 + fr;
  int r = gc >> 7, c = gc & 127;
  int k0 = kk * 32 + fq * 8;
  ushort_t o[8];
#pragma unroll
  for (int j = 0; j < 8; ++j) {
    int k = k0 + j;
    float v;
    if (r < RR) {
      size_t st = (size_t)K * CC;
      size_t p = (size_t)k * CC + c;
      v = comp[r * BB + 0] * basis[p] + comp[r * BB + 1] * basis[st + p]
        + comp[r * BB + 2] * basis[2 * st + p] + comp[r * BB + 3] * basis[3 * st + p];
    } else {
      v = root[(size_t)k * CC + c];
    }
    o[j] = f2bf(v);
  }
  *(u16x8*)(Wt + (size_t)f * 8) = *(const u16x8*)o;
}

// Row-stripe GEMM: block = 64 rows, loops over all 18 column tiles.
// X tile in LDS once; W tile reg-staged (issue ct+1 while computing ct).
template <int K>
__global__ __launch_bounds__(256) void gemm2_k(const ushort_t* __restrict__ Xb,
                                               const ushort_t* __restrict__ Wt,
                                               ushort_t* __restrict__ hr,
                                               float* __restrict__ aggroot) {
  constexpr int XST = K + 8;              // LDS row stride (bf16 elems)
  constexpr int SEGS = K / 8;             // u16x8 segments per X row
  constexpr int LOADS = (64 * K) / 2048;  // W u16x8 loads per thread (4 or 8)
  __shared__ ushort_t xs[64 * XST];
  __shared__ ushort_t wls[64 * K];
  int t = threadIdx.x;
  int wave = t >> 6, lane = t & 63;
  int fr = lane & 15, fq = lane >> 4;
  int row0 = blockIdx.x * 64;

  // X tile -> LDS (once)
  for (int idx = t; idx < 64 * SEGS; idx += 256) {
    int row = idx / SEGS, seg = idx - row * SEGS;
    int gr = row0 + row;
    if (gr >= NN) gr = NN - 1;
    u16x8 v = *(const u16x8*)(Xb + (size_t)gr * 256 + seg * 8);
    *(u16x8*)(xs + row * XST + seg * 8) = v;
  }

  // preload W tile 0 into regs
  u16x8 wreg[LOADS];
#pragma unroll
  for (int q = 0; q < LOADS; ++q)
    wreg[q] = *(const u16x8*)(Wt + ((size_t)q * 256 + t) * 8);

  for (int ct = 0; ct < NT; ++ct) {
    __syncthreads();  // prev compute done -> wls free (also fences X writes on ct=0)
#pragma unroll
    for (int q = 0; q < LOADS; ++q)
      *(u16x8*)(wls + ((size_t)q * 256 + t) * 8) = wreg[q];
    __syncthreads();
    if (ct + 1 < NT) {
      const ushort_t* nw = Wt + (size_t)(ct + 1) * 64 * K;
#pragma unroll
      for (int q = 0; q < LOADS; ++q)
        wreg[q] = *(const u16x8*)(nw + ((size_t)q * 256 + t) * 8);
    }
    f32x4 acc[4];
#pragma unroll
    for (int cb = 0; cb < 4; ++cb) acc[cb] = (f32x4){0.f, 0.f, 0.f, 0.f};
#pragma unroll
    for (int kk = 0; kk < K / 32; ++kk) {
      bf16x8 a = *(const bf16x8*)(xs + (size_t)(wave * 16 + fr) * XST + kk * 32 + fq * 8);
#pragma unroll
      for (int cb = 0; cb < 4; ++cb) {
        bf16x8 b = *(const bf16x8*)(wls + ((kk * 4 + cb) * 64 + lane) * 8);
        acc[cb] = __builtin_amdgcn_mfma_f32_16x16x32_bf16(a, b, acc[cb], 0, 0, 0);
      }
    }
    int r = (ct * 64) >> 7;  // slot uniform per ct
#pragma unroll
    for (int cb = 0; cb < 4; ++cb) {
      int gc = ct * 64 + cb * 16 + fr;
      int c = gc & 127;
#pragma unroll
      for (int j = 0; j < 4; ++j) {
        int n = row0 + wave * 16 + fq * 4 + j;
        if (n < NN) {
          if (r < RR) hr[((size_t)r * NN + n) * CC + c] = f2bf(acc[cb][j]);
          else        aggroot[(size_t)n * CC + c] = acc[cb][j];
        }
      }
    }
  }
}

extern "C" void kernel_launch(void* const* d_in, const int* in_sizes, int n_in,
                              void* d_out, int out_size, void* d_ws, size_t ws_size,
                              hipStream_t stream) {
  const int* ei = (const int*)d_in[0];
  const int* et = (const int*)d_in[1];
  const float* basis1 = (const float*)d_in[2];
  const float* comp1 = (const float*)d_in[3];
  const float* root1 = (const float*)d_in[4];
  const float* bias1 = (const float*)d_in[5];
  const float* basis_b0 = (const float*)d_in[6];
  const float* comp_b0 = (const float*)d_in[7];
  const float* root_b0 = (const float*)d_in[8];
  const float* bias_b0 = (const float*)d_in[9];
  const float* basis_b1 = (const float*)d_in[10];
  const float* comp_b1 = (const float*)d_in[11];
  const float* root_b1 = (const float*)d_in[12];
  const float* bias_b1 = (const float*)d_in[13];
  float* out = (float*)d_out;  // [N][384] h3 storage
  char* ws = (char*)d_ws;

  uint2* payload = (uint2*)ws;                                  // E * 8B
  float* aggroot = (float*)(payload + EE);                      // N*C f32
  ushort_t* hr = (ushort_t*)(aggroot + (size_t)NN * CC);        // 8*N*C bf16
  ushort_t* xb = hr + (size_t)RR * NN * CC;                     // N*256 bf16
  ushort_t* wt = xb + (size_t)NN * 256;                         // NCOL*256 bf16
  int* cnt_rd = (int*)(wt + (size_t)NCOL * 256);                // R*N int
  int* cur = cnt_rd + (size_t)RR * NN;                          // N int
  int* off = cur + NN;                                          // N+1 int
  int* bsum = off + NN + 1;
  int* bbase = bsum + 256;
  size_t need = (size_t)((char*)(bbase + 256) - ws);
  if (ws_size < need) return;

  // --- CSR build ---
  zero_int_k<<<(RR * NN + NN + 255) / 256, 256, 0, stream>>>(cnt_rd, RR * NN + NN);
  count_k<<<(EE + 255) / 256, 256, 0, stream>>>(ei, et, cnt_rd);
  scanA_k<<<NB, 256, 0, stream>>>(cnt_rd, off, bsum);
  scanB_k<<<1, 256, 0, stream>>>(bsum, bbase);
  scanC_k<<<NB, 256, 0, stream>>>(off, bbase);
  fill_k<<<(EE + 255) / 256, 256, 0, stream>>>(ei, et, cnt_rd, off, cur, payload);

  const int NC_BLKS = (NN * CC + 255) / 256;
  const int AG_BLKS = (NN + 3) / 4;
  const int GE_BLKS = (NN + 63) / 64;  // 782

  // --- layer 1 ---
  makehr1_k<<<NC_BLKS, 256, 0, stream>>>(basis1, comp1, hr);
  aggr_k<<<AG_BLKS, 256, 0, stream>>>(off, payload, hr, root1, bias1, out, 0, xb, 0);

  // --- layer 2 (K=128) ---
  makew2_k<<<(NT * (CC / 32) * 256 + 255) / 256, 256, 0, stream>>>(basis_b0, comp_b0, root_b0, wt, CC);
  gemm2_k<128><<<GE_BLKS, 256, 0, stream>>>(xb, wt, hr, aggroot);
  aggr_k<<<AG_BLKS, 256, 0, stream>>>(off, payload, hr, aggroot, bias_b0, out, CC, xb, CC);

  // --- layer 3 (K=256) ---
  makew2_k<<<(NT * (2 * CC / 32) * 256 + 255) / 256, 256, 0, stream>>>(basis_b1, comp_b1, root_b1, wt, 2 * CC);
  gemm2_k<256><<<GE_BLKS, 256, 0, stream>>>(xb, wt, hr, aggroot);
  aggr_sm_k<<<AG_BLKS, 256, 0, stream>>>(off, payload, hr, aggroot, bias_b1, out);
}